// Round 18
// baseline (207.324 us; speedup 1.0000x reference)
//
#include <hip/hip_runtime.h>
#include <hip/hip_bf16.h>
#include <stdint.h>

// ---------------- problem constants ----------------
#define BB 2
#define TT 2048
#define DD 2048
#define HH 16
#define KVH 8
#define HDIM 128
#define BT (BB*TT)            // 4096
#define NQKV (HH*HDIM + 2*KVH*HDIM) // 4096
#define TQ (TT/128)           // 16 q-blocks of 128 rows
#define ATT_SCALE 0.08838834764831845f
#define RMS_EPS 1e-6f

typedef __bf16 bf16;
typedef __bf16 bf16x8 __attribute__((ext_vector_type(8)));
typedef __bf16 bf16x4 __attribute__((ext_vector_type(4)));
typedef __bf16 bf16x2 __attribute__((ext_vector_type(2)));
typedef float  f32x4  __attribute__((ext_vector_type(4)));
typedef float  f32x16 __attribute__((ext_vector_type(16)));
typedef unsigned u32x4 __attribute__((ext_vector_type(4)));

// async global->LDS, 16B per lane. LDS dest = wave-uniform base + lane*16.
__device__ __forceinline__ void gl_lds16(const void* g, const void* l) {
  __builtin_amdgcn_global_load_lds(
      (const __attribute__((address_space(1))) void*)(uintptr_t)g,
      (__attribute__((address_space(3))) void*)(uint32_t)(uintptr_t)l,
      16, 0, 0);
}

// pack two f32 -> one u32 of 2 bf16 (lo, hi)
__device__ __forceinline__ unsigned pkbf(float lo, float hi) {
  bf16x2 t = { (bf16)lo, (bf16)hi };
  return __builtin_bit_cast(unsigned, t);
}

// ---------------- fused prep: x cast + 4 weight transpose-casts ----------------
// grid (32, 32, 5): z=0 x-cast; z=1 wq^T; z=2 wk^T; z=3 wv^T; z=4 wo^T
__global__ __launch_bounds__(256) void prep_k(const float* __restrict__ x,
                                              const float* __restrict__ wq,
                                              const float* __restrict__ wk,
                                              const float* __restrict__ wv,
                                              const float* __restrict__ wo,
                                              bf16* __restrict__ xb,
                                              bf16* __restrict__ Wt,
                                              bf16* __restrict__ Wot) {
  const int z = blockIdx.z;
  if (z == 0) {
    int id = (blockIdx.y * 32 + blockIdx.x) * 2048 + threadIdx.x;
#pragma unroll
    for (int i = 0; i < 8; ++i) {
      int idx = id + i * 256;
      float4 v = ((const float4*)x)[idx];
      bf16x4 o4 = { (bf16)v.x, (bf16)v.y, (bf16)v.z, (bf16)v.w };
      *(bf16x4*)(xb + (size_t)idx * 4) = o4;
    }
    return;
  }
  const float* in; bf16* out; int C;
  const int R = 2048;
  if (z == 1)      { in = wq; out = Wt;                          C = 2048; }
  else if (z == 2) { in = wk; out = Wt + (size_t)2048 * 2048;    C = 1024; }
  else if (z == 3) { in = wv; out = Wt + (size_t)3072 * 2048;    C = 1024; }
  else             { in = wo; out = Wot;                         C = 2048; }
  int c0 = blockIdx.x * 64, r0 = blockIdx.y * 64;
  if (c0 >= C) return;
  __shared__ float tile[64][65];
  const int lane = threadIdx.x & 63, wid = threadIdx.x >> 6;
#pragma unroll
  for (int i = 0; i < 16; ++i) {
    int rr = wid * 16 + i;
    tile[rr][lane] = in[(size_t)(r0 + rr) * C + c0 + lane];
  }
  __syncthreads();
#pragma unroll
  for (int i = 0; i < 16; ++i) {
    int cc = wid * 16 + i;
    out[(size_t)(c0 + cc) * R + r0 + lane] = (bf16)tile[lane][cc];
  }
}

// ---------------- QKV GEMM 256x128, BK=64, 8-phase + FUSED RMSNorm/RoPE epilogue --
// 256x128 tile (3-section {A0,A1,B} schedule cloned from out-proj, which runs
// ~2x the per-FLOP rate of the 256x256 version): grid 16x32 = 512 blocks (2
// sequential blocks/CU smooths barrier stalls). Each 128-col tile is ONE head:
// bx<16 -> Q head bx; 16..23 -> K head bx-16; >=24 -> V head bx-24 (stored
// direct-transposed). RoPE partner (d^64) lives in wave wid^1 at the same acc
// index -> same LDS exchange as before, only 2 quadrants.
__global__ __launch_bounds__(512, 1)
void gemmqkv128_k(const bf16* __restrict__ A, const bf16* __restrict__ Bt,
                  bf16* __restrict__ qro, bf16* __restrict__ kro,
                  bf16* __restrict__ vbt,
                  const float* __restrict__ qn_w, const float* __restrict__ kn_w,
                  const float* __restrict__ sinb, const float* __restrict__ cosb,
                  int M, int N, int K) {
  __shared__ bf16 S[2 * 3 * 128 * 64];   // 96 KiB
  const int tid = threadIdx.x, lane = tid & 63, wid = tid >> 6;
  const int lr = lane & 15, lq = lane >> 4;
  const int wrow = wid >> 1, wcol = wid & 1;

  const int nwg = gridDim.x;
  const int o = blockIdx.x;
  const int ns = (o & 7) * (nwg >> 3) + (o >> 3);
  const int GX = N >> 7;                  // 32
  const int by = ns / GX, bx = ns % GX;

  const int NT = K >> 6;
  const bf16* Ab = A + (size_t)(by * 256) * K;
  const bf16* Bb = Bt + (size_t)(bx * 128) * K;

  const int srow = tid >> 3;
  const size_t soff = (size_t)srow * K + (((tid & 7) ^ (srow & 7)) * 8);
  const int ldst0 = wid * 512;

  auto STAGE = [&](int sec, int t_) {
    int tc = t_ < NT ? t_ : NT - 1;
    const bf16* src = (sec == 2 ? Bb : Ab + (size_t)(sec * 128) * K) + soff + tc * 64;
    bf16* dst = S + ((t_ & 1) * 3 + sec) * 8192 + ldst0;
#pragma unroll
    for (int i = 0; i < 2; ++i)
      gl_lds16(src + (size_t)(i * 64) * K, dst + i * 4096);
  };

  bf16x8 af[2][2][2];   // [mh][m][ks]
  bf16x8 bfr[4][2];     // [n][ks]
  f32x4 acc[2][2][4] = {};  // [mh][m][n]

  auto LOAD_A1 = [&](int buf, int mh) {
    const bf16* base = S + (buf * 3 + mh) * 8192;
#pragma unroll
    for (int m = 0; m < 2; ++m) {
      int ra = wrow * 32 + m * 16 + lr;
#pragma unroll
      for (int ks = 0; ks < 2; ++ks)
        af[mh][m][ks] = *(const bf16x8*)(base + ra * 64 + (((ks * 4 + lq) ^ (ra & 7)) * 8));
    }
  };
  auto LOAD_B = [&](int buf, int ng) {
    const bf16* base = S + (buf * 3 + 2) * 8192;
#pragma unroll
    for (int n = 2 * ng; n < 2 * ng + 2; ++n) {
      int rb = wcol * 64 + n * 16 + lr;
#pragma unroll
      for (int ks = 0; ks < 2; ++ks)
        bfr[n][ks] = *(const bf16x8*)(base + rb * 64 + (((ks * 4 + lq) ^ (rb & 7)) * 8));
    }
  };
  auto MFMA_Q = [&](int mh, int ng) {
#pragma unroll
    for (int m = 0; m < 2; ++m)
#pragma unroll
      for (int n = 2 * ng; n < 2 * ng + 2; ++n)
#pragma unroll
        for (int ks = 0; ks < 2; ++ks)
          acc[mh][m][n] = __builtin_amdgcn_mfma_f32_16x16x32_bf16(
              af[mh][m][ks], bfr[n][ks], acc[mh][m][n], 0, 0, 0);
  };

  STAGE(0, 0); STAGE(1, 0); STAGE(2, 0);
  STAGE(0, 1); STAGE(1, 1);
  asm volatile("s_waitcnt vmcnt(4)" ::: "memory");
  __builtin_amdgcn_sched_barrier(0);
  __builtin_amdgcn_s_barrier();

  for (int t = 0; t < NT; ++t) {
    const int buf = t & 1;
    LOAD_A1(buf, 0);
    LOAD_B(buf, 0);
    STAGE(2, t + 1);
    __builtin_amdgcn_s_barrier();
    asm volatile("s_waitcnt lgkmcnt(0)" ::: "memory");
    __builtin_amdgcn_sched_barrier(0);
    __builtin_amdgcn_s_setprio(1);
    MFMA_Q(0, 0);
    __builtin_amdgcn_s_setprio(0);
    __builtin_amdgcn_s_barrier();
    LOAD_A1(buf, 1);
    STAGE(0, t + 2);
    __builtin_amdgcn_s_barrier();
    asm volatile("s_waitcnt lgkmcnt(0)" ::: "memory");
    __builtin_amdgcn_sched_barrier(0);
    __builtin_amdgcn_s_setprio(1);
    MFMA_Q(1, 0);
    __builtin_amdgcn_s_setprio(0);
    __builtin_amdgcn_s_barrier();
    LOAD_B(buf, 1);
    STAGE(1, t + 2);
    __builtin_amdgcn_s_barrier();
    asm volatile("s_waitcnt lgkmcnt(0)" ::: "memory");
    __builtin_amdgcn_sched_barrier(0);
    __builtin_amdgcn_s_setprio(1);
    MFMA_Q(1, 1);
    __builtin_amdgcn_s_setprio(0);
    __builtin_amdgcn_s_barrier();
    asm volatile("s_waitcnt vmcnt(4)" ::: "memory");
    __builtin_amdgcn_sched_barrier(0);
    __builtin_amdgcn_s_barrier();
    __builtin_amdgcn_s_setprio(1);
    MFMA_Q(0, 1);
    __builtin_amdgcn_s_setprio(0);
    __builtin_amdgcn_s_barrier();
  }

  // ---------------- fused epilogue (one head per block) ----------------
  __syncthreads();                    // S free; drain everything
  float* ex  = (float*)S;             // [32][512] raw-value exchange (64 KB)
  float* ssb = ex + 16384;            // [2][128] cross-wave ss

  if (bx >= 24) {                     // V: direct-transposed bf16x4 stores
    const int kvh = bx - 24;
#pragma unroll
    for (int mh = 0; mh < 2; ++mh)
#pragma unroll
      for (int m = 0; m < 2; ++m) {
        int bt0 = by * 256 + mh * 128 + wrow * 32 + m * 16 + lq * 4;
        int bb = bt0 >> 11, t2 = bt0 & 2047;
#pragma unroll
        for (int n = 0; n < 4; ++n) {
          int d = wcol * 64 + n * 16 + lr;
          bf16x4 o4 = { (bf16)acc[mh][m][n][0], (bf16)acc[mh][m][n][1],
                        (bf16)acc[mh][m][n][2], (bf16)acc[mh][m][n][3] };
          *(bf16x4*)(vbt + ((size_t)(bb * KVH + kvh) * HDIM + d) * TT + t2) = o4;
        }
      }
    return;
  }

  const bool isQ = (bx < 16);
  const float* wn = isQ ? qn_w : kn_w;
  float w_own[4], w_par[4];
#pragma unroll
  for (int n = 0; n < 4; ++n) {
    w_own[n] = wn[wcol * 64 + n * 16 + lr];
    w_par[n] = wn[(wcol ^ 1) * 64 + n * 16 + lr];
  }

#pragma unroll
  for (int mh = 0; mh < 2; ++mh) {
    float ssp[2][4];
#pragma unroll
    for (int m = 0; m < 2; ++m)
#pragma unroll
      for (int j = 0; j < 4; ++j) {
        float s = 0.f;
#pragma unroll
        for (int n = 0; n < 4; ++n) { float v = acc[mh][m][n][j]; s += v * v; }
#pragma unroll
        for (int off = 1; off < 16; off <<= 1) s += __shfl_xor(s, off, 64);
        ssp[m][j] = s;
      }
    if (lr == 0) {
#pragma unroll
      for (int m = 0; m < 2; ++m)
#pragma unroll
        for (int j = 0; j < 4; ++j)
          ssb[wcol * 128 + wrow * 32 + m * 16 + lq * 4 + j] = ssp[m][j];
    }
#pragma unroll
    for (int m = 0; m < 2; ++m)
#pragma unroll
      for (int n = 0; n < 4; ++n)
#pragma unroll
        for (int j = 0; j < 4; ++j)
          ex[(m * 16 + n * 4 + j) * 512 + wid * 64 + lane] = acc[mh][m][n][j];
    __syncthreads();

#pragma unroll
    for (int m = 0; m < 2; ++m)
#pragma unroll
      for (int j = 0; j < 4; ++j) {
        float tot = ssp[m][j] + ssb[(wcol ^ 1) * 128 + wrow * 32 + m * 16 + lq * 4 + j];
        float rms = rsqrtf(tot * (1.0f / 128.0f) + RMS_EPS);
        int bt = by * 256 + mh * 128 + wrow * 32 + m * 16 + lq * 4 + j;
        int bb = bt >> 11, t2 = bt & 2047;
        bf16* dst;
        if (isQ) dst = qro + (size_t)bt * (HH * HDIM) + bx * 128;
        else     dst = kro + ((size_t)(bb * KVH + (bx - 16)) * TT + t2) * HDIM;
#pragma unroll
        for (int n = 0; n < 4; ++n) {
          float sv = sinb[bt * 64 + n * 16 + lr];
          float cv = cosb[bt * 64 + n * 16 + lr];
          float own = acc[mh][m][n][j] * rms * w_own[n];
          float par = ex[(m * 16 + n * 4 + j) * 512 + (wid ^ 1) * 64 + lane] * rms * w_par[n];
          float ov = wcol ? (own * cv + par * sv) : (own * cv - par * sv);
          dst[wcol * 64 + n * 16 + lr] = (bf16)ov;
        }
      }
    __syncthreads();   // before next mh reuses ex/ssb
  }
}

// ---------------- GEMM 256x128, BK=64, 8-phase counted-vmcnt (out-proj) ------
template <int OUT_F32>
__global__ __launch_bounds__(512, 1)
void gemm256x128_k(const bf16* __restrict__ A, const bf16* __restrict__ Bt,
                   void* __restrict__ Cout, int M, int N, int K) {
  __shared__ bf16 S[2 * 3 * 128 * 64];   // 96 KiB
  const int tid = threadIdx.x, lane = tid & 63, wid = tid >> 6;
  const int lr = lane & 15, lq = lane >> 4;
  const int wrow = wid >> 1, wcol = wid & 1;

  const int nwg = gridDim.x;
  const int o = blockIdx.x;
  const int ns = (o & 7) * (nwg >> 3) + (o >> 3);
  const int GX = N >> 7;
  const int by = ns / GX, bx = ns % GX;

  const int NT = K >> 6;
  const bf16* Ab = A + (size_t)(by * 256) * K;
  const bf16* Bb = Bt + (size_t)(bx * 128) * K;

  const int srow = tid >> 3;
  const size_t soff = (size_t)srow * K + (((tid & 7) ^ (srow & 7)) * 8);
  const int ldst0 = wid * 512;

  auto STAGE = [&](int sec, int t_) {
    int tc = t_ < NT ? t_ : NT - 1;
    const bf16* src = (sec == 2 ? Bb : Ab + (size_t)(sec * 128) * K) + soff + tc * 64;
    bf16* dst = S + ((t_ & 1) * 3 + sec) * 8192 + ldst0;
#pragma unroll
    for (int i = 0; i < 2; ++i)
      gl_lds16(src + (size_t)(i * 64) * K, dst + i * 4096);
  };

  bf16x8 af[2][2][2];   // [mh][m][ks]
  bf16x8 bfr[4][2];     // [n][ks]
  f32x4 acc[2][2][4] = {};  // [mh][m][n]

  auto LOAD_A1 = [&](int buf, int mh) {
    const bf16* base = S + (buf * 3 + mh) * 8192;
#pragma unroll
    for (int m = 0; m < 2; ++m) {
      int ra = wrow * 32 + m * 16 + lr;
#pragma unroll
      for (int ks = 0; ks < 2; ++ks)
        af[mh][m][ks] = *(const bf16x8*)(base + ra * 64 + (((ks * 4 + lq) ^ (ra & 7)) * 8));
    }
  };
  auto LOAD_B = [&](int buf, int ng) {
    const bf16* base = S + (buf * 3 + 2) * 8192;
#pragma unroll
    for (int n = 2 * ng; n < 2 * ng + 2; ++n) {
      int rb = wcol * 64 + n * 16 + lr;
#pragma unroll
      for (int ks = 0; ks < 2; ++ks)
        bfr[n][ks] = *(const bf16x8*)(base + rb * 64 + (((ks * 4 + lq) ^ (rb & 7)) * 8));
    }
  };
  auto MFMA_Q = [&](int mh, int ng) {
#pragma unroll
    for (int m = 0; m < 2; ++m)
#pragma unroll
      for (int n = 2 * ng; n < 2 * ng + 2; ++n)
#pragma unroll
        for (int ks = 0; ks < 2; ++ks)
          acc[mh][m][n] = __builtin_amdgcn_mfma_f32_16x16x32_bf16(
              af[mh][m][ks], bfr[n][ks], acc[mh][m][n], 0, 0, 0);
  };

  STAGE(0, 0); STAGE(1, 0); STAGE(2, 0);
  STAGE(0, 1); STAGE(1, 1);
  asm volatile("s_waitcnt vmcnt(4)" ::: "memory");
  __builtin_amdgcn_sched_barrier(0);
  __builtin_amdgcn_s_barrier();

  for (int t = 0; t < NT; ++t) {
    const int buf = t & 1;
    LOAD_A1(buf, 0);
    LOAD_B(buf, 0);
    STAGE(2, t + 1);
    __builtin_amdgcn_s_barrier();
    asm volatile("s_waitcnt lgkmcnt(0)" ::: "memory");
    __builtin_amdgcn_sched_barrier(0);
    __builtin_amdgcn_s_setprio(1);
    MFMA_Q(0, 0);
    __builtin_amdgcn_s_setprio(0);
    __builtin_amdgcn_s_barrier();
    LOAD_A1(buf, 1);
    STAGE(0, t + 2);
    __builtin_amdgcn_s_barrier();
    asm volatile("s_waitcnt lgkmcnt(0)" ::: "memory");
    __builtin_amdgcn_sched_barrier(0);
    __builtin_amdgcn_s_setprio(1);
    MFMA_Q(1, 0);
    __builtin_amdgcn_s_setprio(0);
    __builtin_amdgcn_s_barrier();
    LOAD_B(buf, 1);
    STAGE(1, t + 2);
    __builtin_amdgcn_s_barrier();
    asm volatile("s_waitcnt lgkmcnt(0)" ::: "memory");
    __builtin_amdgcn_sched_barrier(0);
    __builtin_amdgcn_s_setprio(1);
    MFMA_Q(1, 1);
    __builtin_amdgcn_s_setprio(0);
    __builtin_amdgcn_s_barrier();
    asm volatile("s_waitcnt vmcnt(4)" ::: "memory");
    __builtin_amdgcn_sched_barrier(0);
    __builtin_amdgcn_s_barrier();
    __builtin_amdgcn_s_setprio(1);
    MFMA_Q(0, 1);
    __builtin_amdgcn_s_setprio(0);
    __builtin_amdgcn_s_barrier();
  }

#pragma unroll
  for (int mh = 0; mh < 2; ++mh)
#pragma unroll
    for (int m = 0; m < 2; ++m)
#pragma unroll
      for (int n = 0; n < 4; ++n)
#pragma unroll
        for (int j = 0; j < 4; ++j) {
          int row = by * 256 + mh * 128 + wrow * 32 + m * 16 + lq * 4 + j;
          int col = bx * 128 + wcol * 64 + n * 16 + lr;
          if (OUT_F32) ((float*)Cout)[(size_t)row * N + col] = acc[mh][m][n][j];
          else         ((bf16*)Cout)[(size_t)row * N + col] = (bf16)acc[mh][m][n][j];
        }
}

// ---------------- GQA causal flash attention (attn8 structure, proven 75us) ----
__global__ __launch_bounds__(256, 2)
void attn17_k(const bf16* __restrict__ qr, const bf16* __restrict__ kr2,
              const bf16* __restrict__ vbt, bf16* __restrict__ ao) {
  __shared__ bf16 Ks[2][64 * 128];
  __shared__ bf16 Vs[2][128 * 64];
  const int tid = threadIdx.x, lane = tid & 63, wid = tid >> 6;
  const int l31 = lane & 31, hi = lane >> 5;
  const int h = blockIdx.y, b = blockIdx.z;
  const int qt = (b & 1) ? (TQ - 1 - blockIdx.x) : blockIdx.x;
  const int kvh = h >> 1;            // N_REP = 2
  const int q0w = qt * 128 + wid * 32;
  const int qg = q0w + l31;
  const int nt = 2 * qt + 2;

  const bf16* Kbase = kr2 + ((size_t)(b * KVH + kvh)) * TT * HDIM;
  const bf16* Vbase = vbt + ((size_t)(b * KVH + kvh)) * ((size_t)HDIM * TT);

  auto STAGE = [&](int bufi, int kt) {
#pragma unroll
    for (int i = 0; i < 4; ++i) {
      int u = i * 256 + tid;          // 0..1023
      int krow = u >> 4, kcc = u & 15;
      gl_lds16(Kbase + (size_t)(kt * 64 + krow) * HDIM + ((kcc ^ (krow & 15)) * 8),
               &Ks[bufi][(i * 256 + wid * 64) * 8]);
      int vrow = u >> 3, vcc = u & 7;
      gl_lds16(Vbase + (size_t)vrow * TT + kt * 64 + ((vcc ^ (vrow & 7)) * 8),
               &Vs[bufi][(i * 256 + wid * 64) * 8]);
    }
  };

  bf16x8 qf[8];
  const bf16* qrow = &qr[(((size_t)(b * TT + qg)) * HH + h) * HDIM];
#pragma unroll
  for (int ks = 0; ks < 8; ++ks)
    qf[ks] = *(const bf16x8*)(qrow + ks * 16 + hi * 8);

  f32x16 accO[4] = {};
  float m = -INFINITY, lsum = 0.f;
  const float SC2 = ATT_SCALE * 1.4426950408889634f;   // exp2 domain

  int buf = 0;
  STAGE(0, 0);
  __syncthreads();

  for (int kt = 0; kt < nt; ++kt) {
    if (kt + 1 < nt) STAGE(buf ^ 1, kt + 1);

    if (kt * 64 <= q0w + 31) {   // wave-uniform skip of fully-masked tiles
      const char* Kb = (const char*)&Ks[buf][0];
      const char* Vb = (const char*)&Vs[buf][0];
      const bool domask = (kt * 64 + 63) > q0w;        // diagonal band?

      // ---- S^T = K Q^T ----
      f32x16 sacc[2];
#pragma unroll
      for (int ct = 0; ct < 2; ++ct) {
#pragma unroll
        for (int j = 0; j < 16; ++j) sacc[ct][j] = 0.f;
        int krow = ct * 32 + l31;
#pragma unroll
        for (int ks = 0; ks < 8; ++ks) {
          bf16x8 kf = *(const bf16x8*)(Kb + krow * 256 + (((2 * ks + hi) ^ (krow & 15)) * 16));
          sacc[ct] = __builtin_amdgcn_mfma_f32_32x32x16_bf16(kf, qf[ks], sacc[ct], 0, 0, 0);
        }
      }

      // ---- scale (+ mask only on diagonal), in-lane max ----
      float p[2][16];
      float pmx = -INFINITY;
      if (domask) {
#pragma unroll
        for (int ct = 0; ct < 2; ++ct) {
          int lim = qg - (kt * 64 + ct * 32 + 4 * hi);
#pragma unroll
          for (int r = 0; r < 16; ++r) {
            const int crow0 = (r & 3) + 8 * (r >> 2);
            float v = sacc[ct][r] * SC2;
            v = (crow0 <= lim) ? v : -INFINITY;
            p[ct][r] = v;
            pmx = fmaxf(pmx, v);
          }
        }
      } else {
#pragma unroll
        for (int ct = 0; ct < 2; ++ct)
#pragma unroll
          for (int r = 0; r < 16; ++r) {
            float v = sacc[ct][r] * SC2;
            p[ct][r] = v;
            pmx = fmaxf(pmx, v);
          }
      }
      pmx = fmaxf(pmx, __shfl_xor(pmx, 32, 64));

      // ---- defer-max (T13), 8 nats = 11.54 bits ----
      if (__any(pmx > m + 11.54f)) {
        float mnew = fmaxf(m, pmx);
        float alpha = exp2f(m - mnew);
        m = mnew;
        lsum *= alpha;
        int ai = __builtin_bit_cast(int, alpha);
#pragma unroll
        for (int r = 0; r < 16; ++r) {
          const int crow = (r & 3) + 8 * (r >> 2) + 4 * hi;
          float av = __builtin_bit_cast(float, __builtin_amdgcn_ds_bpermute(crow << 2, ai));
#pragma unroll
          for (int n = 0; n < 4; ++n) accO[n][r] *= av;
        }
      }

      // ---- P = exp2(S - m), in-lane sum ----
      float rsum = 0.f;
#pragma unroll
      for (int ct = 0; ct < 2; ++ct)
#pragma unroll
        for (int r = 0; r < 16; ++r) {
          float e = exp2f(p[ct][r] - m);
          p[ct][r] = e;
          rsum += e;
        }
      rsum += __shfl_xor(rsum, 32, 64);
      lsum += rsum;

      // ---- pack P -> PV A-fragments (half-exchanges, in-register) ----
      bf16x8 pa[4];
#pragma unroll
      for (int ct = 0; ct < 2; ++ct) {
        unsigned W[8];
#pragma unroll
        for (int mi = 0; mi < 8; ++mi)
          W[mi] = pkbf(p[ct][2 * mi], p[ct][2 * mi + 1]);
#pragma unroll
        for (int a = 0; a < 2; ++a) {
          unsigned s0 = __shfl_xor(W[4 * a + 0], 32, 64);
          unsigned s1 = __shfl_xor(W[4 * a + 1], 32, 64);
          unsigned s2 = __shfl_xor(W[4 * a + 2], 32, 64);
          unsigned s3 = __shfl_xor(W[4 * a + 3], 32, 64);
          u32x4 wv;
          wv[0] = hi ? s2 : W[4 * a + 0];
          wv[1] = hi ? s3 : W[4 * a + 1];
          wv[2] = hi ? W[4 * a + 2] : s0;
          wv[3] = hi ? W[4 * a + 3] : s1;
          pa[ct * 2 + a] = __builtin_bit_cast(bf16x8, wv);
        }
      }

      // ---- O += P V ----
#pragma unroll
      for (int n = 0; n < 4; ++n) {
        int vrow = n * 32 + l31;
#pragma unroll
        for (int ks = 0; ks < 4; ++ks) {
          bf16x8 vf = *(const bf16x8*)(Vb + vrow * 128 + (((2 * ks + hi) ^ (vrow & 7)) * 16));
          accO[n] = __builtin_amdgcn_mfma_f32_32x32x16_bf16(pa[ks], vf, accO[n], 0, 0, 0);
        }
      }
    }

    __syncthreads();
    buf ^= 1;
  }

  // ---- epilogue: O /= l (row-broadcast via bpermute) ----
  float inv = 1.0f / lsum;
  int ii = __builtin_bit_cast(int, inv);
#pragma unroll
  for (int n = 0; n < 4; ++n)
#pragma unroll
    for (int r = 0; r < 16; ++r) {
      const int crow = (r & 3) + 8 * (r >> 2) + 4 * hi;
      float av = __builtin_bit_cast(float, __builtin_amdgcn_ds_bpermute(crow << 2, ii));
      size_t idx = (((size_t)(b * TT + q0w + crow)) * HH + h) * HDIM + n * 32 + l31;
      ao[idx] = (bf16)(accO[n][r] * av);
    }
}

// ---------------- launcher ----------------
extern "C" void kernel_launch(void* const* d_in, const int* in_sizes, int n_in,
                              void* d_out, int out_size, void* d_ws, size_t ws_size,
                              hipStream_t stream) {
  const float* x    = (const float*)d_in[0];
  const float* wq   = (const float*)d_in[1];
  const float* wk   = (const float*)d_in[2];
  const float* wv   = (const float*)d_in[3];
  const float* wo   = (const float*)d_in[4];
  const float* qn_w = (const float*)d_in[5];
  const float* kn_w = (const float*)d_in[6];
  const float* sinb = (const float*)d_in[7];
  const float* cosb = (const float*)d_in[8];
  float* out = (float*)d_out;

  char* ws = (char*)d_ws;
  size_t off = 0;
  auto alloc = [&](size_t bytes) {
    char* p = ws + off;
    off += (bytes + 255) & ~(size_t)255;
    return p;
  };
  bf16* xb  = (bf16*)alloc((size_t)BT * DD * 2);       // x bf16 (reused as attn out)
  bf16* Wt  = (bf16*)alloc((size_t)NQKV * DD * 2);     // [wq|wk|wv]^T
  bf16* Wot = (bf16*)alloc((size_t)DD * DD * 2);       // wo^T
  bf16* qro = (bf16*)alloc((size_t)BT * HH * HDIM * 2);    // q rope'd (B,T,H,HD)
  bf16* kro = (bf16*)alloc((size_t)BT * KVH * HDIM * 2);   // (B,KVH,T,HD)
  bf16* vbt = (bf16*)alloc((size_t)BT * KVH * HDIM * 2);   // (B,KVH,HD,T) direct
  bf16* aob = xb;   // alias: xb dead after QKV GEMM
  (void)ws_size; (void)in_sizes; (void)n_in; (void)out_size;

  // fused prep: x cast + 4 weight transposes (one launch, 64x64 tiles)
  prep_k<<<dim3(32, 32, 5), 256, 0, stream>>>(x, wq, wk, wv, wo, xb, Wt, Wot);

  // QKV GEMM (256x128 tile, one head per block) with fused RMSNorm+RoPE epilogue
  gemmqkv128_k<<<dim3((BT / 256) * (NQKV / 128)), 512, 0, stream>>>(
      xb, Wt, qro, kro, vbt, qn_w, kn_w, sinb, cosb, BT, NQKV, DD);

  attn17_k<<<dim3(TQ, HH, BB), 256, 0, stream>>>(qro, kro, vbt, aob);

  // out-proj: 256x128-tile 8-phase (M=4096, N=2048 -> 256 blocks, full GPU)
  gemm256x128_k<1><<<dim3((BT / 256) * (DD / 128)), 512, 0, stream>>>(aob, Wot, out, BT, DD, DD);
}

// Round 19
// 200.207 us; speedup vs baseline: 1.0355x; 1.0355x over previous
//
#include <hip/hip_runtime.h>
#include <hip/hip_bf16.h>
#include <stdint.h>

// ---------------- problem constants ----------------
#define BB 2
#define TT 2048
#define DD 2048
#define HH 16
#define KVH 8
#define HDIM 128
#define BT (BB*TT)            // 4096
#define NQKV (HH*HDIM + 2*KVH*HDIM) // 4096
#define TQ (TT/128)           // 16 q-blocks of 128 rows
#define ATT_SCALE 0.08838834764831845f
#define RMS_EPS 1e-6f

typedef __bf16 bf16;
typedef __bf16 bf16x8 __attribute__((ext_vector_type(8)));
typedef __bf16 bf16x4 __attribute__((ext_vector_type(4)));
typedef __bf16 bf16x2 __attribute__((ext_vector_type(2)));
typedef float  f32x4  __attribute__((ext_vector_type(4)));
typedef float  f32x16 __attribute__((ext_vector_type(16)));
typedef unsigned u32x4 __attribute__((ext_vector_type(4)));

// async global->LDS, 16B per lane. LDS dest = wave-uniform base + lane*16.
__device__ __forceinline__ void gl_lds16(const void* g, const void* l) {
  __builtin_amdgcn_global_load_lds(
      (const __attribute__((address_space(1))) void*)(uintptr_t)g,
      (__attribute__((address_space(3))) void*)(uint32_t)(uintptr_t)l,
      16, 0, 0);
}

// pack two f32 -> one u32 of 2 bf16 (lo, hi)
__device__ __forceinline__ unsigned pkbf(float lo, float hi) {
  bf16x2 t = { (bf16)lo, (bf16)hi };
  return __builtin_bit_cast(unsigned, t);
}

// ---------------- fused prep: x cast + 4 weight transpose-casts ----------------
// grid (32, 32, 5): z=0 x-cast; z=1 wq^T; z=2 wk^T; z=3 wv^T; z=4 wo^T
__global__ __launch_bounds__(256) void prep_k(const float* __restrict__ x,
                                              const float* __restrict__ wq,
                                              const float* __restrict__ wk,
                                              const float* __restrict__ wv,
                                              const float* __restrict__ wo,
                                              bf16* __restrict__ xb,
                                              bf16* __restrict__ Wt,
                                              bf16* __restrict__ Wot) {
  const int z = blockIdx.z;
  if (z == 0) {
    int id = (blockIdx.y * 32 + blockIdx.x) * 2048 + threadIdx.x;
#pragma unroll
    for (int i = 0; i < 8; ++i) {
      int idx = id + i * 256;
      float4 v = ((const float4*)x)[idx];
      bf16x4 o4 = { (bf16)v.x, (bf16)v.y, (bf16)v.z, (bf16)v.w };
      *(bf16x4*)(xb + (size_t)idx * 4) = o4;
    }
    return;
  }
  const float* in; bf16* out; int C;
  const int R = 2048;
  if (z == 1)      { in = wq; out = Wt;                          C = 2048; }
  else if (z == 2) { in = wk; out = Wt + (size_t)2048 * 2048;    C = 1024; }
  else if (z == 3) { in = wv; out = Wt + (size_t)3072 * 2048;    C = 1024; }
  else             { in = wo; out = Wot;                         C = 2048; }
  int c0 = blockIdx.x * 64, r0 = blockIdx.y * 64;
  if (c0 >= C) return;
  __shared__ float tile[64][65];
  const int lane = threadIdx.x & 63, wid = threadIdx.x >> 6;
#pragma unroll
  for (int i = 0; i < 16; ++i) {
    int rr = wid * 16 + i;
    tile[rr][lane] = in[(size_t)(r0 + rr) * C + c0 + lane];
  }
  __syncthreads();
#pragma unroll
  for (int i = 0; i < 16; ++i) {
    int cc = wid * 16 + i;
    out[(size_t)(c0 + cc) * R + r0 + lane] = (bf16)tile[lane][cc];
  }
}

// ---------------- QKV GEMM 256x256, BK=64, 8-phase + FUSED RMSNorm/RoPE epilogue --
// V blocks store DIRECTLY TRANSPOSED to vbt (B,KVH,HD,T): per (qd,m,n) the 4
// j-values are 4 consecutive t at fixed d -> one contiguous bf16x4 store.
__global__ __launch_bounds__(512, 2)
void gemm256qkv_k(const bf16* __restrict__ A, const bf16* __restrict__ Bt,
                  bf16* __restrict__ qro, bf16* __restrict__ kro,
                  bf16* __restrict__ vbt,
                  const float* __restrict__ qn_w, const float* __restrict__ kn_w,
                  const float* __restrict__ sinb, const float* __restrict__ cosb,
                  int M, int N, int K) {
  __shared__ bf16 S[2 * 2 * 2 * 128 * 64];   // 128 KiB
  const int tid = threadIdx.x, lane = tid & 63, wid = tid >> 6;
  const int lr = lane & 15, lq = lane >> 4;
  const int wrow = wid >> 1, wcol = wid & 1;

  const int nwg = gridDim.x;
  const int o = blockIdx.x;
  const int ns = (o & 7) * (nwg >> 3) + (o >> 3);
  const int GX = N >> 8;
  const int by = ns / GX, bx = ns % GX;

  const int NT = K >> 6;
  const bf16* Ab = A + (size_t)(by * 256) * K;
  const bf16* Bb = Bt + (size_t)(bx * 256) * K;

  const int srow = tid >> 3;
  const size_t soff = (size_t)srow * K + (((tid & 7) ^ (srow & 7)) * 8);
  const int ldst0 = wid * 512;

  auto STAGE = [&](int op, int h, int t_) {
    int tc = t_ < NT ? t_ : NT - 1;
    const bf16* src = (op ? Bb : Ab) + soff + (size_t)(h * 128) * K + tc * 64;
    bf16* dst = S + ((((((t_ & 1) << 1) | op) << 1) | h) << 13) + ldst0;
#pragma unroll
    for (int i = 0; i < 2; ++i)
      gl_lds16(src + (size_t)(i * 64) * K, dst + i * 4096);
  };

  bf16x8 af[2][2][2];   // [mh][m][ks]
  bf16x8 bfr[4][2];     // [n][ks]
  f32x4 acc[4][2][4] = {};  // [quad][m][n]

  auto LOAD_A1 = [&](int buf, int mh) {
    const bf16* base = S + (((buf << 2) | mh) << 13);
#pragma unroll
    for (int m = 0; m < 2; ++m) {
      int ra = wrow * 32 + m * 16 + lr;
#pragma unroll
      for (int ks = 0; ks < 2; ++ks)
        af[mh][m][ks] = *(const bf16x8*)(base + ra * 64 + (((ks * 4 + lq) ^ (ra & 7)) * 8));
    }
  };
  auto LOAD_B = [&](int buf, int nh) {
    const bf16* base = S + (((buf << 2) | 2 | nh) << 13);
#pragma unroll
    for (int n = 0; n < 4; ++n) {
      int rb = wcol * 64 + n * 16 + lr;
#pragma unroll
      for (int ks = 0; ks < 2; ++ks)
        bfr[n][ks] = *(const bf16x8*)(base + rb * 64 + (((ks * 4 + lq) ^ (rb & 7)) * 8));
    }
  };
  auto MFMA_Q = [&](int qd, int mh) {
#pragma unroll
    for (int m = 0; m < 2; ++m)
#pragma unroll
      for (int n = 0; n < 4; ++n)
#pragma unroll
        for (int ks = 0; ks < 2; ++ks)
          acc[qd][m][n] = __builtin_amdgcn_mfma_f32_16x16x32_bf16(
              af[mh][m][ks], bfr[n][ks], acc[qd][m][n], 0, 0, 0);
  };

  STAGE(0, 0, 0); STAGE(0, 1, 0); STAGE(1, 0, 0); STAGE(1, 1, 0);
  STAGE(0, 0, 1); STAGE(0, 1, 1); STAGE(1, 0, 1);
  asm volatile("s_waitcnt vmcnt(6)" ::: "memory");
  __builtin_amdgcn_sched_barrier(0);
  __builtin_amdgcn_s_barrier();

  for (int t = 0; t < NT; ++t) {
    const int buf = t & 1;
    // ph1: Q(0,0); reads A0 (4) + B0 (8); stage B1(t+1)
    LOAD_A1(buf, 0);
    LOAD_B(buf, 0);
    STAGE(1, 1, t + 1);
    __builtin_amdgcn_s_barrier();
    asm volatile("s_waitcnt lgkmcnt(0)" ::: "memory");
    __builtin_amdgcn_sched_barrier(0);
    __builtin_amdgcn_s_setprio(1);
    MFMA_Q(0, 0);
    __builtin_amdgcn_s_setprio(0);
    __builtin_amdgcn_s_barrier();
    // ph2: Q(1,0); reads A1 (4); stage A0(t+2)
    LOAD_A1(buf, 1);
    STAGE(0, 0, t + 2);
    __builtin_amdgcn_s_barrier();
    asm volatile("s_waitcnt lgkmcnt(0)" ::: "memory");
    __builtin_amdgcn_sched_barrier(0);
    __builtin_amdgcn_s_setprio(1);
    MFMA_Q(1, 1);
    __builtin_amdgcn_s_setprio(0);
    __builtin_amdgcn_s_barrier();
    // ph3: Q(1,1); reads B1 (8); stage A1(t+2)
    LOAD_B(buf, 1);
    STAGE(0, 1, t + 2);
    __builtin_amdgcn_s_barrier();
    asm volatile("s_waitcnt lgkmcnt(0)" ::: "memory");
    __builtin_amdgcn_sched_barrier(0);
    __builtin_amdgcn_s_setprio(1);
    MFMA_Q(2, 1);
    __builtin_amdgcn_s_setprio(0);
    __builtin_amdgcn_s_barrier();
    // ph4: Q(0,1); cached; stage B0(t+2); vmcnt(6) = tile t+1 landed
    STAGE(1, 0, t + 2);
    asm volatile("s_waitcnt vmcnt(6)" ::: "memory");
    __builtin_amdgcn_sched_barrier(0);
    __builtin_amdgcn_s_barrier();
    __builtin_amdgcn_s_setprio(1);
    MFMA_Q(3, 0);
    __builtin_amdgcn_s_setprio(0);
    __builtin_amdgcn_s_barrier();
  }

  // ---------------- fused epilogue ----------------
  __syncthreads();                    // S free; drain everything
  float* ex  = (float*)S;             // [32][512] raw-value exchange
  float* ssb = ex + 16384;            // [2][128] cross-wave ss

  if (bx >= 12) {                     // V: direct-transposed bf16x4 stores
#pragma unroll
    for (int qd = 0; qd < 4; ++qd) {
      const int mh = (qd == 1 || qd == 2) ? 1 : 0;
      const int nh = (qd >= 2) ? 1 : 0;
      const int kvh = (bx - 12) * 2 + nh;
#pragma unroll
      for (int m = 0; m < 2; ++m) {
        int bt0 = by * 256 + mh * 128 + wrow * 32 + m * 16 + lq * 4;
        int bb = bt0 >> 11, t2 = bt0 & 2047;
#pragma unroll
        for (int n = 0; n < 4; ++n) {
          int d = wcol * 64 + n * 16 + lr;
          bf16x4 o4 = { (bf16)acc[qd][m][n][0], (bf16)acc[qd][m][n][1],
                        (bf16)acc[qd][m][n][2], (bf16)acc[qd][m][n][3] };
          *(bf16x4*)(vbt + ((size_t)(bb * KVH + kvh) * HDIM + d) * TT + t2) = o4;
        }
      }
    }
    return;
  }

  const bool isQ = (bx < 8);
  const float* wn = isQ ? qn_w : kn_w;
  float w_own[4], w_par[4];
#pragma unroll
  for (int n = 0; n < 4; ++n) {
    w_own[n] = wn[wcol * 64 + n * 16 + lr];
    w_par[n] = wn[(wcol ^ 1) * 64 + n * 16 + lr];
  }

#pragma unroll
  for (int qd = 0; qd < 4; ++qd) {
    const int mh = (qd == 1 || qd == 2) ? 1 : 0;
    const int nh = (qd >= 2) ? 1 : 0;
    float ssp[2][4];
#pragma unroll
    for (int m = 0; m < 2; ++m)
#pragma unroll
      for (int j = 0; j < 4; ++j) {
        float s = 0.f;
#pragma unroll
        for (int n = 0; n < 4; ++n) { float v = acc[qd][m][n][j]; s += v * v; }
#pragma unroll
        for (int off = 1; off < 16; off <<= 1) s += __shfl_xor(s, off, 64);
        ssp[m][j] = s;
      }
    if (lr == 0) {
#pragma unroll
      for (int m = 0; m < 2; ++m)
#pragma unroll
        for (int j = 0; j < 4; ++j)
          ssb[wcol * 128 + wrow * 32 + m * 16 + lq * 4 + j] = ssp[m][j];
    }
#pragma unroll
    for (int m = 0; m < 2; ++m)
#pragma unroll
      for (int n = 0; n < 4; ++n)
#pragma unroll
        for (int j = 0; j < 4; ++j)
          ex[(m * 16 + n * 4 + j) * 512 + wid * 64 + lane] = acc[qd][m][n][j];
    __syncthreads();

#pragma unroll
    for (int m = 0; m < 2; ++m)
#pragma unroll
      for (int j = 0; j < 4; ++j) {
        float tot = ssp[m][j] + ssb[(wcol ^ 1) * 128 + wrow * 32 + m * 16 + lq * 4 + j];
        float rms = rsqrtf(tot * (1.0f / 128.0f) + RMS_EPS);
        int bt = by * 256 + mh * 128 + wrow * 32 + m * 16 + lq * 4 + j;
        int bb = bt >> 11, t2 = bt & 2047;
        bf16* dst;
        if (isQ) dst = qro + (size_t)bt * (HH * HDIM) + (bx * 2 + nh) * 128;
        else     dst = kro + ((size_t)(bb * KVH + (bx - 8) * 2 + nh) * TT + t2) * HDIM;
#pragma unroll
        for (int n = 0; n < 4; ++n) {
          float sv = sinb[bt * 64 + n * 16 + lr];
          float cv = cosb[bt * 64 + n * 16 + lr];
          float own = acc[qd][m][n][j] * rms * w_own[n];
          float par = ex[(m * 16 + n * 4 + j) * 512 + (wid ^ 1) * 64 + lane] * rms * w_par[n];
          float ov = wcol ? (own * cv + par * sv) : (own * cv - par * sv);
          dst[wcol * 64 + n * 16 + lr] = (bf16)ov;
        }
      }
    __syncthreads();   // before next quadrant reuses ex/ssb
  }
}

// ---------------- GEMM 256x128, BK=64, 8-phase counted-vmcnt (out-proj) ------
template <int OUT_F32>
__global__ __launch_bounds__(512, 1)
void gemm256x128_k(const bf16* __restrict__ A, const bf16* __restrict__ Bt,
                   void* __restrict__ Cout, int M, int N, int K) {
  __shared__ bf16 S[2 * 3 * 128 * 64];   // 96 KiB
  const int tid = threadIdx.x, lane = tid & 63, wid = tid >> 6;
  const int lr = lane & 15, lq = lane >> 4;
  const int wrow = wid >> 1, wcol = wid & 1;

  const int nwg = gridDim.x;
  const int o = blockIdx.x;
  const int ns = (o & 7) * (nwg >> 3) + (o >> 3);
  const int GX = N >> 7;
  const int by = ns / GX, bx = ns % GX;

  const int NT = K >> 6;
  const bf16* Ab = A + (size_t)(by * 256) * K;
  const bf16* Bb = Bt + (size_t)(bx * 128) * K;

  const int srow = tid >> 3;
  const size_t soff = (size_t)srow * K + (((tid & 7) ^ (srow & 7)) * 8);
  const int ldst0 = wid * 512;

  auto STAGE = [&](int sec, int t_) {
    int tc = t_ < NT ? t_ : NT - 1;
    const bf16* src = (sec == 2 ? Bb : Ab + (size_t)(sec * 128) * K) + soff + tc * 64;
    bf16* dst = S + ((t_ & 1) * 3 + sec) * 8192 + ldst0;
#pragma unroll
    for (int i = 0; i < 2; ++i)
      gl_lds16(src + (size_t)(i * 64) * K, dst + i * 4096);
  };

  bf16x8 af[2][2][2];   // [mh][m][ks]
  bf16x8 bfr[4][2];     // [n][ks]
  f32x4 acc[2][2][4] = {};  // [mh][m][n]

  auto LOAD_A1 = [&](int buf, int mh) {
    const bf16* base = S + (buf * 3 + mh) * 8192;
#pragma unroll
    for (int m = 0; m < 2; ++m) {
      int ra = wrow * 32 + m * 16 + lr;
#pragma unroll
      for (int ks = 0; ks < 2; ++ks)
        af[mh][m][ks] = *(const bf16x8*)(base + ra * 64 + (((ks * 4 + lq) ^ (ra & 7)) * 8));
    }
  };
  auto LOAD_B = [&](int buf, int ng) {
    const bf16* base = S + (buf * 3 + 2) * 8192;
#pragma unroll
    for (int n = 2 * ng; n < 2 * ng + 2; ++n) {
      int rb = wcol * 64 + n * 16 + lr;
#pragma unroll
      for (int ks = 0; ks < 2; ++ks)
        bfr[n][ks] = *(const bf16x8*)(base + rb * 64 + (((ks * 4 + lq) ^ (rb & 7)) * 8));
    }
  };
  auto MFMA_Q = [&](int mh, int ng) {
#pragma unroll
    for (int m = 0; m < 2; ++m)
#pragma unroll
      for (int n = 2 * ng; n < 2 * ng + 2; ++n)
#pragma unroll
        for (int ks = 0; ks < 2; ++ks)
          acc[mh][m][n] = __builtin_amdgcn_mfma_f32_16x16x32_bf16(
              af[mh][m][ks], bfr[n][ks], acc[mh][m][n], 0, 0, 0);
  };

  STAGE(0, 0); STAGE(1, 0); STAGE(2, 0);
  STAGE(0, 1); STAGE(1, 1);
  asm volatile("s_waitcnt vmcnt(4)" ::: "memory");
  __builtin_amdgcn_sched_barrier(0);
  __builtin_amdgcn_s_barrier();

  for (int t = 0; t < NT; ++t) {
    const int buf = t & 1;
    LOAD_A1(buf, 0);
    LOAD_B(buf, 0);
    STAGE(2, t + 1);
    __builtin_amdgcn_s_barrier();
    asm volatile("s_waitcnt lgkmcnt(0)" ::: "memory");
    __builtin_amdgcn_sched_barrier(0);
    __builtin_amdgcn_s_setprio(1);
    MFMA_Q(0, 0);
    __builtin_amdgcn_s_setprio(0);
    __builtin_amdgcn_s_barrier();
    LOAD_A1(buf, 1);
    STAGE(0, t + 2);
    __builtin_amdgcn_s_barrier();
    asm volatile("s_waitcnt lgkmcnt(0)" ::: "memory");
    __builtin_amdgcn_sched_barrier(0);
    __builtin_amdgcn_s_setprio(1);
    MFMA_Q(1, 0);
    __builtin_amdgcn_s_setprio(0);
    __builtin_amdgcn_s_barrier();
    LOAD_B(buf, 1);
    STAGE(1, t + 2);
    __builtin_amdgcn_s_barrier();
    asm volatile("s_waitcnt lgkmcnt(0)" ::: "memory");
    __builtin_amdgcn_sched_barrier(0);
    __builtin_amdgcn_s_setprio(1);
    MFMA_Q(1, 1);
    __builtin_amdgcn_s_setprio(0);
    __builtin_amdgcn_s_barrier();
    asm volatile("s_waitcnt vmcnt(4)" ::: "memory");
    __builtin_amdgcn_sched_barrier(0);
    __builtin_amdgcn_s_barrier();
    __builtin_amdgcn_s_setprio(1);
    MFMA_Q(0, 1);
    __builtin_amdgcn_s_setprio(0);
    __builtin_amdgcn_s_barrier();
  }

#pragma unroll
  for (int mh = 0; mh < 2; ++mh)
#pragma unroll
    for (int m = 0; m < 2; ++m)
#pragma unroll
      for (int n = 0; n < 4; ++n)
#pragma unroll
        for (int j = 0; j < 4; ++j) {
          int row = by * 256 + mh * 128 + wrow * 32 + m * 16 + lq * 4 + j;
          int col = bx * 128 + wcol * 64 + n * 16 + lr;
          if (OUT_F32) ((float*)Cout)[(size_t)row * N + col] = acc[mh][m][n][j];
          else         ((bf16*)Cout)[(size_t)row * N + col] = (bf16)acc[mh][m][n][j];
        }
}

// ---------------- GQA causal flash attention (attn8 structure, proven 75us) ----
__global__ __launch_bounds__(256, 2)
void attn18_k(const bf16* __restrict__ qr, const bf16* __restrict__ kr2,
              const bf16* __restrict__ vbt, bf16* __restrict__ ao) {
  __shared__ bf16 Ks[2][64 * 128];
  __shared__ bf16 Vs[2][128 * 64];
  const int tid = threadIdx.x, lane = tid & 63, wid = tid >> 6;
  const int l31 = lane & 31, hi = lane >> 5;
  const int h = blockIdx.y, b = blockIdx.z;
  const int qt = (b & 1) ? (TQ - 1 - blockIdx.x) : blockIdx.x;
  const int kvh = h >> 1;            // N_REP = 2
  const int q0w = qt * 128 + wid * 32;
  const int qg = q0w + l31;
  const int nt = 2 * qt + 2;

  const bf16* Kbase = kr2 + ((size_t)(b * KVH + kvh)) * TT * HDIM;
  const bf16* Vbase = vbt + ((size_t)(b * KVH + kvh)) * ((size_t)HDIM * TT);

  auto STAGE = [&](int bufi, int kt) {
#pragma unroll
    for (int i = 0; i < 4; ++i) {
      int u = i * 256 + tid;          // 0..1023
      int krow = u >> 4, kcc = u & 15;
      gl_lds16(Kbase + (size_t)(kt * 64 + krow) * HDIM + ((kcc ^ (krow & 15)) * 8),
               &Ks[bufi][(i * 256 + wid * 64) * 8]);
      int vrow = u >> 3, vcc = u & 7;
      gl_lds16(Vbase + (size_t)vrow * TT + kt * 64 + ((vcc ^ (vrow & 7)) * 8),
               &Vs[bufi][(i * 256 + wid * 64) * 8]);
    }
  };

  bf16x8 qf[8];
  const bf16* qrow = &qr[(((size_t)(b * TT + qg)) * HH + h) * HDIM];
#pragma unroll
  for (int ks = 0; ks < 8; ++ks)
    qf[ks] = *(const bf16x8*)(qrow + ks * 16 + hi * 8);

  f32x16 accO[4] = {};
  float m = -INFINITY, lsum = 0.f;
  const float SC2 = ATT_SCALE * 1.4426950408889634f;   // exp2 domain

  int buf = 0;
  STAGE(0, 0);
  __syncthreads();

  for (int kt = 0; kt < nt; ++kt) {
    if (kt + 1 < nt) STAGE(buf ^ 1, kt + 1);

    if (kt * 64 <= q0w + 31) {   // wave-uniform skip of fully-masked tiles
      const char* Kb = (const char*)&Ks[buf][0];
      const char* Vb = (const char*)&Vs[buf][0];
      const bool domask = (kt * 64 + 63) > q0w;        // diagonal band?

      // ---- S^T = K Q^T ----
      f32x16 sacc[2];
#pragma unroll
      for (int ct = 0; ct < 2; ++ct) {
#pragma unroll
        for (int j = 0; j < 16; ++j) sacc[ct][j] = 0.f;
        int krow = ct * 32 + l31;
#pragma unroll
        for (int ks = 0; ks < 8; ++ks) {
          bf16x8 kf = *(const bf16x8*)(Kb + krow * 256 + (((2 * ks + hi) ^ (krow & 15)) * 16));
          sacc[ct] = __builtin_amdgcn_mfma_f32_32x32x16_bf16(kf, qf[ks], sacc[ct], 0, 0, 0);
        }
      }

      // ---- scale (+ mask only on diagonal), in-lane max ----
      float p[2][16];
      float pmx = -INFINITY;
      if (domask) {
#pragma unroll
        for (int ct = 0; ct < 2; ++ct) {
          int lim = qg - (kt * 64 + ct * 32 + 4 * hi);
#pragma unroll
          for (int r = 0; r < 16; ++r) {
            const int crow0 = (r & 3) + 8 * (r >> 2);
            float v = sacc[ct][r] * SC2;
            v = (crow0 <= lim) ? v : -INFINITY;
            p[ct][r] = v;
            pmx = fmaxf(pmx, v);
          }
        }
      } else {
#pragma unroll
        for (int ct = 0; ct < 2; ++ct)
#pragma unroll
          for (int r = 0; r < 16; ++r) {
            float v = sacc[ct][r] * SC2;
            p[ct][r] = v;
            pmx = fmaxf(pmx, v);
          }
      }
      pmx = fmaxf(pmx, __shfl_xor(pmx, 32, 64));

      // ---- defer-max (T13), 8 nats = 11.54 bits ----
      if (__any(pmx > m + 11.54f)) {
        float mnew = fmaxf(m, pmx);
        float alpha = exp2f(m - mnew);
        m = mnew;
        lsum *= alpha;
        int ai = __builtin_bit_cast(int, alpha);
#pragma unroll
        for (int r = 0; r < 16; ++r) {
          const int crow = (r & 3) + 8 * (r >> 2) + 4 * hi;
          float av = __builtin_bit_cast(float, __builtin_amdgcn_ds_bpermute(crow << 2, ai));
#pragma unroll
          for (int n = 0; n < 4; ++n) accO[n][r] *= av;
        }
      }

      // ---- P = exp2(S - m), in-lane sum ----
      float rsum = 0.f;
#pragma unroll
      for (int ct = 0; ct < 2; ++ct)
#pragma unroll
        for (int r = 0; r < 16; ++r) {
          float e = exp2f(p[ct][r] - m);
          p[ct][r] = e;
          rsum += e;
        }
      rsum += __shfl_xor(rsum, 32, 64);
      lsum += rsum;

      // ---- pack P -> PV A-fragments (half-exchanges, in-register) ----
      bf16x8 pa[4];
#pragma unroll
      for (int ct = 0; ct < 2; ++ct) {
        unsigned W[8];
#pragma unroll
        for (int mi = 0; mi < 8; ++mi)
          W[mi] = pkbf(p[ct][2 * mi], p[ct][2 * mi + 1]);
#pragma unroll
        for (int a = 0; a < 2; ++a) {
          unsigned s0 = __shfl_xor(W[4 * a + 0], 32, 64);
          unsigned s1 = __shfl_xor(W[4 * a + 1], 32, 64);
          unsigned s2 = __shfl_xor(W[4 * a + 2], 32, 64);
          unsigned s3 = __shfl_xor(W[4 * a + 3], 32, 64);
          u32x4 wv;
          wv[0] = hi ? s2 : W[4 * a + 0];
          wv[1] = hi ? s3 : W[4 * a + 1];
          wv[2] = hi ? W[4 * a + 2] : s0;
          wv[3] = hi ? W[4 * a + 3] : s1;
          pa[ct * 2 + a] = __builtin_bit_cast(bf16x8, wv);
        }
      }

      // ---- O += P V ----
#pragma unroll
      for (int n = 0; n < 4; ++n) {
        int vrow = n * 32 + l31;
#pragma unroll
        for (int ks = 0; ks < 4; ++ks) {
          bf16x8 vf = *(const bf16x8*)(Vb + vrow * 128 + (((2 * ks + hi) ^ (vrow & 7)) * 16));
          accO[n] = __builtin_amdgcn_mfma_f32_32x32x16_bf16(pa[ks], vf, accO[n], 0, 0, 0);
        }
      }
    }

    __syncthreads();
    buf ^= 1;
  }

  // ---- epilogue: O /= l (row-broadcast via bpermute) ----
  float inv = 1.0f / lsum;
  int ii = __builtin_bit_cast(int, inv);
#pragma unroll
  for (int n = 0; n < 4; ++n)
#pragma unroll
    for (int r = 0; r < 16; ++r) {
      const int crow = (r & 3) + 8 * (r >> 2) + 4 * hi;
      float av = __builtin_bit_cast(float, __builtin_amdgcn_ds_bpermute(crow << 2, ii));
      size_t idx = (((size_t)(b * TT + q0w + crow)) * HH + h) * HDIM + n * 32 + l31;
      ao[idx] = (bf16)(accO[n][r] * av);
    }
}

// ---------------- launcher ----------------
extern "C" void kernel_launch(void* const* d_in, const int* in_sizes, int n_in,
                              void* d_out, int out_size, void* d_ws, size_t ws_size,
                              hipStream_t stream) {
  const float* x    = (const float*)d_in[0];
  const float* wq   = (const float*)d_in[1];
  const float* wk   = (const float*)d_in[2];
  const float* wv   = (const float*)d_in[3];
  const float* wo   = (const float*)d_in[4];
  const float* qn_w = (const float*)d_in[5];
  const float* kn_w = (const float*)d_in[6];
  const float* sinb = (const float*)d_in[7];
  const float* cosb = (const float*)d_in[8];
  float* out = (float*)d_out;

  char* ws = (char*)d_ws;
  size_t off = 0;
  auto alloc = [&](size_t bytes) {
    char* p = ws + off;
    off += (bytes + 255) & ~(size_t)255;
    return p;
  };
  bf16* xb  = (bf16*)alloc((size_t)BT * DD * 2);       // x bf16 (reused as attn out)
  bf16* Wt  = (bf16*)alloc((size_t)NQKV * DD * 2);     // [wq|wk|wv]^T
  bf16* Wot = (bf16*)alloc((size_t)DD * DD * 2);       // wo^T
  bf16* qro = (bf16*)alloc((size_t)BT * HH * HDIM * 2);    // q rope'd (B,T,H,HD)
  bf16* kro = (bf16*)alloc((size_t)BT * KVH * HDIM * 2);   // (B,KVH,T,HD)
  bf16* vbt = (bf16*)alloc((size_t)BT * KVH * HDIM * 2);   // (B,KVH,HD,T) direct
  bf16* aob = xb;   // alias: xb dead after QKV GEMM
  (void)ws_size; (void)in_sizes; (void)n_in; (void)out_size;

  // fused prep: x cast + 4 weight transposes (one launch, 64x64 tiles)
  prep_k<<<dim3(32, 32, 5), 256, 0, stream>>>(x, wq, wk, wv, wo, xb, Wt, Wot);

  // QKV GEMM (256x256 tile) with fused RMSNorm+RoPE epilogue; V pre-transposed
  gemm256qkv_k<<<dim3((BT / 256) * (NQKV / 256)), 512, 0, stream>>>(
      xb, Wt, qro, kro, vbt, qn_w, kn_w, sinb, cosb, BT, NQKV, DD);

  attn18_k<<<dim3(TQ, HH, BB), 256, 0, stream>>>(qro, kro, vbt, aob);

  // out-proj: 256x128-tile 8-phase (M=4096, N=2048 -> 256 blocks, full GPU)
  gemm256x128_k<1><<<dim3((BT / 256) * (DD / 128)), 512, 0, stream>>>(aob, Wot, out, BT, DD, DD);
}